// Round 4
// baseline (246.818 us; speedup 1.0000x reference)
//
#include <hip/hip_runtime.h>
#include <hip/hip_bf16.h>
#include <math.h>

#define Hh 128   // hidden
#define Nn 32    // docs
#define Ll 128   // doc_len
#define W1S 384  // 3H
#define PAD 136  // bf16 elems per LDS row: 272B stride -> 2-way (free) frag reads

typedef __attribute__((ext_vector_type(8))) short short8;
typedef __attribute__((ext_vector_type(4))) float floatx4;

__device__ __forceinline__ unsigned short f2bf(float x) {
  __hip_bfloat16 h = __float2bfloat16(x);
  return __builtin_bit_cast(unsigned short, h);
}
__device__ __forceinline__ float bf2f(short s) {
  unsigned int u = ((unsigned int)(unsigned short)s) << 16;
  return __builtin_bit_cast(float, u);
}
__device__ __forceinline__ short8 pack8(float4 a, float4 b) {
  short8 r;
  r[0] = (short)f2bf(a.x); r[1] = (short)f2bf(a.y);
  r[2] = (short)f2bf(a.z); r[3] = (short)f2bf(a.w);
  r[4] = (short)f2bf(b.x); r[5] = (short)f2bf(b.y);
  r[6] = (short)f2bf(b.z); r[7] = (short)f2bf(b.w);
  return r;
}

// Grid 128: block b -> n = b>>2, which = (b>>1)&1 (0:Bt 1:Ct), mh = b&1 (M-half).
// scale folded at staging; b1 folded into Bt so k_main skips it. (unchanged)
__launch_bounds__(256, 2)
__global__ void k_prep(const float* __restrict__ wei, const int* __restrict__ wmask,
                       const float* __restrict__ doc, const float* __restrict__ q,
                       const float* __restrict__ W1, const float* __restrict__ b1,
                       float* __restrict__ Bt, float* __restrict__ Ct) {
  __shared__ __align__(16) short Wsb[Hh * PAD];   // bf16(W1b or W1c)
  __shared__ __align__(16) short docb[64 * PAD];  // bf16(doc * scale), this block's 64 rows
  __shared__ __align__(16) float red[2][Hh];
  __shared__ __align__(16) float scale[Hh];

  int b = blockIdx.x;
  int n = b >> 2, which = (b >> 1) & 1, mh = b & 1;
  int tid = threadIdx.x;
  const float* docn = doc + (size_t)n * Ll * Hh;
  int e8 = (tid & 15) * 8;

  float4 dreg[4][2];
#pragma unroll
  for (int p = 0; p < 4; ++p) {
    int row = mh * 64 + p * 16 + (tid >> 4);
    const float4* dp = (const float4*)(docn + (size_t)row * Hh + e8);
    dreg[p][0] = dp[0]; dreg[p][1] = dp[1];
  }
#pragma unroll
  for (int p = 0; p < 8; ++p) {
    int row = p * 16 + (tid >> 4);
    const float4* wp = (const float4*)(W1 + (size_t)row * W1S + (which + 1) * Hh + e8);
    *(short8*)(Wsb + row * PAD + e8) = pack8(wp[0], wp[1]);
  }
  if (which == 1) {
    if (tid < Hh) scale[tid] = q[(n >> 3) * Hh + tid];
  } else {
    int e = tid & 127, halfl = tid >> 7;
    const float* wp = wei + (size_t)n * Ll * Hh + (size_t)halfl * 64 * Hh + e;
    const int* mp = wmask + n * Ll + halfl * 64;
    float a = 0.f;
#pragma unroll 16
    for (int l = 0; l < 64; ++l) a = fmaf((float)mp[l], wp[(size_t)l * Hh], a);
    red[halfl][e] = a;
  }
  __syncthreads();
  if (which == 0 && tid < Hh) scale[tid] = red[0][tid] + red[1][tid];
  __syncthreads();
  {
    float s[8];
#pragma unroll
    for (int i = 0; i < 8; ++i) s[i] = scale[e8 + i];
#pragma unroll
    for (int p = 0; p < 4; ++p) {
      int r = p * 16 + (tid >> 4);
      float4 a = dreg[p][0], bq = dreg[p][1];
      a.x *= s[0]; a.y *= s[1]; a.z *= s[2]; a.w *= s[3];
      bq.x *= s[4]; bq.y *= s[5]; bq.z *= s[6]; bq.w *= s[7];
      *(short8*)(docb + r * PAD + e8) = pack8(a, bq);
    }
  }
  __syncthreads();

  int lane = tid & 63, w = tid >> 6;
  int l15 = lane & 15, quad = lane >> 4;
  floatx4 acc[8];
#pragma unroll
  for (int nt = 0; nt < 8; ++nt) acc[nt] = (floatx4){0.f, 0.f, 0.f, 0.f};
#pragma unroll
  for (int c = 0; c < 4; ++c) {
    int eo = c * 32 + quad * 8;
    short8 af = *(const short8*)(docb + (w * 16 + l15) * PAD + eo);
    short8 bfr[8];
#pragma unroll
    for (int nt = 0; nt < 8; ++nt)
      bfr[nt] = *(const short8*)(Wsb + (nt * 16 + l15) * PAD + eo);
#pragma unroll
    for (int nt = 0; nt < 8; ++nt)
      acc[nt] = __builtin_amdgcn_mfma_f32_16x16x32_bf16(af, bfr[nt], acc[nt], 0, 0, 0);
  }

  float* outp = (which ? Ct : Bt) + (size_t)n * Ll * Hh;
#pragma unroll
  for (int nt = 0; nt < 8; ++nt) {
    int g = nt * 16 + l15;
    float badd = which ? 0.f : b1[g];
#pragma unroll
    for (int r = 0; r < 4; ++r) {
      int k = mh * 64 + w * 16 + quad * 4 + r;
      outp[(size_t)k * Hh + g] = acc[nt][r] + badd;
    }
  }
}

// v4: one block per (n, t), t in [0,16): processes 8 COMPACTED unmasked j's
// (jl[8t..8t+7]). 512 blocks, ~79 KB LDS -> 2 blocks/CU -> ALL blocks resident;
// duration ~= single-block latency. Ct reads hoisted out of the j-loop
// (j-invariant). No barriers inside the j-loop.
__launch_bounds__(512, 4)
__global__ void k_main(const float* __restrict__ doc, const int* __restrict__ dmask,
                       const float* __restrict__ W1,
                       const float* __restrict__ w2, const float* __restrict__ b2,
                       const float* __restrict__ Bt, const float* __restrict__ Ct,
                       float* __restrict__ out) {
  __shared__ __align__(16) short As[Hh * PAD];    // bf16(W1a)
  __shared__ __align__(16) short docb[Hh * PAD];  // bf16(doc), raw
  __shared__ __align__(16) float sc[8][Ll];
  __shared__ __align__(16) float scw[8][Ll];
  __shared__ int jl[Ll], ml[Ll], cnts[4];

  int bid = blockIdx.x;
  int n = bid & 31, t = bid >> 5;   // same-n blocks share an XCD slot pattern
  int tid = threadIdx.x;
  int lane = tid & 63, wv = tid >> 6;
  const float* docn = doc + (size_t)n * Ll * Hh;
  const int* dmn = dmask + n * Ll;

  // ballot-compact the mask row (waves 0,1 only)
  int jme = -1, mflag = 0, pre = 0;
  if (wv < 2) {
    jme = (wv << 6) + lane;
    mflag = dmn[jme] != 0;
    unsigned long long bal = __ballot(mflag);
    pre = __popcll(bal & ((1ull << lane) - 1ull));
    if (lane == 0) { int tot = __popcll(bal); cnts[wv] = tot; cnts[2 + wv] = 64 - tot; }
  }
  __syncthreads();
  int cnt = cnts[0] + cnts[1];
  if (wv == 0) { if (mflag) jl[pre] = jme; else ml[lane - pre] = jme; }
  else if (wv == 1) { if (mflag) jl[cnts[0] + pre] = jme; else ml[cnts[2] + (lane - pre)] = jme; }
  __syncthreads();

  // zero-write this block's share of masked rows (looped: masked count can be >64)
  {
    int rr = tid >> 7, h = tid & 127;
    int mcnt = Ll - cnt;
    for (int mi = 4 * t + rr; mi < mcnt; mi += 64)
      out[((size_t)n * Ll + ml[mi]) * Hh + h] = 0.f;
  }
  if (8 * t >= cnt) return;   // block-uniform

  // stage W1a + raw doc
  int e8 = (tid & 15) * 8;
#pragma unroll
  for (int p = 0; p < 4; ++p) {
    int row = p * 32 + (tid >> 4);
    const float4* wp = (const float4*)(W1 + (size_t)row * W1S + e8);
    *(short8*)(As + row * PAD + e8) = pack8(wp[0], wp[1]);
    const float4* dp = (const float4*)(docn + (size_t)row * Hh + e8);
    *(short8*)(docb + row * PAD + e8) = pack8(dp[0], dp[1]);
  }
  __syncthreads();

  int l15 = lane & 15, quad = lane >> 4;

  short8 draw[4];  // this wave's 16 raw doc rows, fragment layout
#pragma unroll
  for (int c = 0; c < 4; ++c)
    draw[c] = *(const short8*)(docb + (wv * 16 + l15) * PAD + c * 32 + quad * 8);

  float w2r[8];
#pragma unroll
  for (int nt = 0; nt < 8; ++nt) w2r[nt] = w2[nt * 16 + l15];

  // j-invariant Ct fragment: ctv[r][nt] = Ct[n, k(wv,quad,r), nt*16+l15]
  const float* ctn = Ct + (size_t)n * Ll * Hh;
  float ctv[4][8];
#pragma unroll
  for (int r = 0; r < 4; ++r) {
    const float* ctp = ctn + (size_t)(wv * 16 + quad * 4 + r) * Hh + l15;
#pragma unroll
    for (int nt = 0; nt < 8; ++nt) ctv[r][nt] = ctp[nt * 16];
  }

  const float c2 = 2.885390081777927f;  // 2*log2(e)

#pragma unroll 2
  for (int jj = 0; jj < 8; ++jj) {
    int idx = 8 * t + jj;
    if (idx >= cnt) break;            // block-uniform
    int j = jl[idx];
    const float* jrow = docn + (size_t)j * Hh;

    floatx4 acc[8];
#pragma unroll
    for (int nt = 0; nt < 8; ++nt) acc[nt] = (floatx4){0.f, 0.f, 0.f, 0.f};
#pragma unroll
    for (int c = 0; c < 4; ++c) {
      int eo = c * 32 + quad * 8;
      const float4* jp = (const float4*)(jrow + eo);  // quad-broadcast, L1-hot
      float4 j0 = jp[0], j1 = jp[1];
      float4 ta, tb;
      ta.x = bf2f(draw[c][0]) * j0.x; ta.y = bf2f(draw[c][1]) * j0.y;
      ta.z = bf2f(draw[c][2]) * j0.z; ta.w = bf2f(draw[c][3]) * j0.w;
      tb.x = bf2f(draw[c][4]) * j1.x; tb.y = bf2f(draw[c][5]) * j1.y;
      tb.z = bf2f(draw[c][6]) * j1.z; tb.w = bf2f(draw[c][7]) * j1.w;
      short8 af = pack8(ta, tb);
#pragma unroll
      for (int nt = 0; nt < 8; ++nt) {
        short8 bfr = *(const short8*)(As + (nt * 16 + l15) * PAD + eo);
        acc[nt] = __builtin_amdgcn_mfma_f32_16x16x32_bf16(af, bfr, acc[nt], 0, 0, 0);
      }
    }

    // epilogue -> sc[jj][k]
    float bbc[8];
    const float* btrow = Bt + ((size_t)n * Ll + j) * Hh;
#pragma unroll
    for (int nt = 0; nt < 8; ++nt) bbc[nt] = btrow[nt * 16 + l15] * c2;
#pragma unroll
    for (int r = 0; r < 4; ++r) {
      int k = wv * 16 + quad * 4 + r;
      float p = 0.f;
#pragma unroll
      for (int nt = 0; nt < 8; ++nt) {
        float s = acc[nt][r] + ctv[r][nt];
        float a2 = fmaf(s, c2, bbc[nt]);
        float e = exp2f(a2);
        float th = fmaf(-2.f, __builtin_amdgcn_rcpf(e + 1.f), 1.f);
        p = fmaf(th, w2r[nt], p);
      }
      p += __shfl_xor(p, 1);
      p += __shfl_xor(p, 2);
      p += __shfl_xor(p, 4);
      p += __shfl_xor(p, 8);
      if (l15 == 0) sc[jj][k] = p;
    }
  }
  __syncthreads();

  // masked softmax: wave wv handles j = jl[8t+wv] (8 waves = 8 j's)
  {
    int idx = 8 * t + wv;
    if (idx < cnt) {
      float b2v = b2[0];
      const float inv = 0.088388347648318447f;  // 1/sqrt(128)
      int m0 = dmn[lane], m1 = dmn[lane + 64];
      float s0 = (sc[wv][lane] + b2v) * inv;
      float s1 = (sc[wv][lane + 64] + b2v) * inv;
      s0 = m0 ? s0 : -1e9f;
      s1 = m1 ? s1 : -1e9f;
      float mx = fmaxf(s0, s1);
#pragma unroll
      for (int off = 32; off; off >>= 1) mx = fmaxf(mx, __shfl_xor(mx, off));
      float ex0 = __expf(s0 - mx), ex1 = __expf(s1 - mx);
      float sm = ex0 + ex1;
#pragma unroll
      for (int off = 32; off; off >>= 1) sm += __shfl_xor(sm, off);
      float rden = 1.f / sm;
      scw[wv][lane] = m0 ? ex0 * rden : 0.f;
      scw[wv][lane + 64] = m1 ? ex1 * rden : 0.f;
    } else {
      scw[wv][lane] = 0.f;
      scw[wv][lane + 64] = 0.f;
    }
  }
  __syncthreads();

  // fused AV: each doc load feeds 8 j-accumulators; k split in 4 quarters
  float* ored = (float*)As;  // [quarter][jj][h], As dead after GEMM
  {
    int qk = tid >> 7, h = tid & 127;   // qk in 0..3, 32 k's each
    const float* dbase = docn + (size_t)qk * 32 * Hh + h;
    float o[8];
#pragma unroll
    for (int jj = 0; jj < 8; ++jj) o[jj] = 0.f;
#pragma unroll
    for (int k4 = 0; k4 < 8; ++k4) {
      float d0 = dbase[(size_t)(k4 * 4 + 0) * Hh];
      float d1 = dbase[(size_t)(k4 * 4 + 1) * Hh];
      float d2 = dbase[(size_t)(k4 * 4 + 2) * Hh];
      float d3 = dbase[(size_t)(k4 * 4 + 3) * Hh];
#pragma unroll
      for (int jj = 0; jj < 8; ++jj) {
        float4 s = *(const float4*)&scw[jj][qk * 32 + k4 * 4];
        o[jj] = fmaf(s.x, d0, o[jj]);
        o[jj] = fmaf(s.y, d1, o[jj]);
        o[jj] = fmaf(s.z, d2, o[jj]);
        o[jj] = fmaf(s.w, d3, o[jj]);
      }
    }
#pragma unroll
    for (int jj = 0; jj < 8; ++jj) ored[(qk * 8 + jj) * Hh + h] = o[jj];
  }
  __syncthreads();
  {
    int h = tid & 127;
#pragma unroll
    for (int it = 0; it < 2; ++it) {
      int jj2 = (tid >> 7) + it * 4;
      int idx = 8 * t + jj2;
      if (idx < cnt) {
        float v = ored[(0 * 8 + jj2) * Hh + h] + ored[(1 * 8 + jj2) * Hh + h] +
                  ored[(2 * 8 + jj2) * Hh + h] + ored[(3 * 8 + jj2) * Hh + h];
        out[((size_t)n * Ll + jl[idx]) * Hh + h] = v;
      }
    }
  }
}

extern "C" void kernel_launch(void* const* d_in, const int* in_sizes, int n_in,
                              void* d_out, int out_size, void* d_ws, size_t ws_size,
                              hipStream_t stream) {
  const float* wei   = (const float*)d_in[0];
  const int*   wmask = (const int*)d_in[1];
  const float* doc   = (const float*)d_in[2];
  const int*   dmask = (const int*)d_in[3];
  const float* q     = (const float*)d_in[4];
  const float* W1    = (const float*)d_in[5];
  const float* b1    = (const float*)d_in[6];
  const float* w2    = (const float*)d_in[7];
  const float* b2    = (const float*)d_in[8];
  float* out = (float*)d_out;

  float* ws = (float*)d_ws;
  float* Bt = ws;                           // N*L*H (b1 folded in)
  float* Ct = Bt + (size_t)Nn * Ll * Hh;    // N*L*H   (total 4.19 MB, unchanged)

  k_prep<<<Nn * 4, 256, 0, stream>>>(wei, wmask, doc, q, W1, b1, Bt, Ct);
  k_main<<<Nn * 16, 512, 0, stream>>>(doc, dmask, W1, w2, b2, Bt, Ct, out);
}

// Round 5
// 130.394 us; speedup vs baseline: 1.8929x; 1.8929x over previous
//
#include <hip/hip_runtime.h>
#include <hip/hip_bf16.h>
#include <math.h>

#define Hh 128   // hidden
#define Nn 32    // docs
#define Ll 128   // doc_len
#define W1S 384  // 3H
#define PAD 136  // bf16 elems per LDS row: 272B stride

typedef __attribute__((ext_vector_type(8))) short short8;
typedef __attribute__((ext_vector_type(4))) float floatx4;

__device__ __forceinline__ unsigned short f2bf(float x) {
  __hip_bfloat16 h = __float2bfloat16(x);
  return __builtin_bit_cast(unsigned short, h);
}
__device__ __forceinline__ float bf2f(short s) {
  unsigned int u = ((unsigned int)(unsigned short)s) << 16;
  return __builtin_bit_cast(float, u);
}
__device__ __forceinline__ short8 pack8(float4 a, float4 b) {
  short8 r;
  r[0] = (short)f2bf(a.x); r[1] = (short)f2bf(a.y);
  r[2] = (short)f2bf(a.z); r[3] = (short)f2bf(a.w);
  r[4] = (short)f2bf(b.x); r[5] = (short)f2bf(b.y);
  r[6] = (short)f2bf(b.z); r[7] = (short)f2bf(b.w);
  return r;
}

// Grid 128: block b -> n = b>>2, which = (b>>1)&1 (0:Bt 1:Ct), mh = b&1 (M-half).
// scale folded at staging; b1 folded into Bt so k_main skips it. (unchanged)
__launch_bounds__(256, 2)
__global__ void k_prep(const float* __restrict__ wei, const int* __restrict__ wmask,
                       const float* __restrict__ doc, const float* __restrict__ q,
                       const float* __restrict__ W1, const float* __restrict__ b1,
                       float* __restrict__ Bt, float* __restrict__ Ct) {
  __shared__ __align__(16) short Wsb[Hh * PAD];   // bf16(W1b or W1c)
  __shared__ __align__(16) short docb[64 * PAD];  // bf16(doc * scale), this block's 64 rows
  __shared__ __align__(16) float red[2][Hh];
  __shared__ __align__(16) float scale[Hh];

  int b = blockIdx.x;
  int n = b >> 2, which = (b >> 1) & 1, mh = b & 1;
  int tid = threadIdx.x;
  const float* docn = doc + (size_t)n * Ll * Hh;
  int e8 = (tid & 15) * 8;

  float4 dreg[4][2];
#pragma unroll
  for (int p = 0; p < 4; ++p) {
    int row = mh * 64 + p * 16 + (tid >> 4);
    const float4* dp = (const float4*)(docn + (size_t)row * Hh + e8);
    dreg[p][0] = dp[0]; dreg[p][1] = dp[1];
  }
#pragma unroll
  for (int p = 0; p < 8; ++p) {
    int row = p * 16 + (tid >> 4);
    const float4* wp = (const float4*)(W1 + (size_t)row * W1S + (which + 1) * Hh + e8);
    *(short8*)(Wsb + row * PAD + e8) = pack8(wp[0], wp[1]);
  }
  if (which == 1) {
    if (tid < Hh) scale[tid] = q[(n >> 3) * Hh + tid];
  } else {
    int e = tid & 127, halfl = tid >> 7;
    const float* wp = wei + (size_t)n * Ll * Hh + (size_t)halfl * 64 * Hh + e;
    const int* mp = wmask + n * Ll + halfl * 64;
    float a = 0.f;
#pragma unroll 16
    for (int l = 0; l < 64; ++l) a = fmaf((float)mp[l], wp[(size_t)l * Hh], a);
    red[halfl][e] = a;
  }
  __syncthreads();
  if (which == 0 && tid < Hh) scale[tid] = red[0][tid] + red[1][tid];
  __syncthreads();
  {
    float s[8];
#pragma unroll
    for (int i = 0; i < 8; ++i) s[i] = scale[e8 + i];
#pragma unroll
    for (int p = 0; p < 4; ++p) {
      int r = p * 16 + (tid >> 4);
      float4 a = dreg[p][0], bq = dreg[p][1];
      a.x *= s[0]; a.y *= s[1]; a.z *= s[2]; a.w *= s[3];
      bq.x *= s[4]; bq.y *= s[5]; bq.z *= s[6]; bq.w *= s[7];
      *(short8*)(docb + r * PAD + e8) = pack8(a, bq);
    }
  }
  __syncthreads();

  int lane = tid & 63, w = tid >> 6;
  int l15 = lane & 15, quad = lane >> 4;
  floatx4 acc[8];
#pragma unroll
  for (int nt = 0; nt < 8; ++nt) acc[nt] = (floatx4){0.f, 0.f, 0.f, 0.f};
#pragma unroll
  for (int c = 0; c < 4; ++c) {
    int eo = c * 32 + quad * 8;
    short8 af = *(const short8*)(docb + (w * 16 + l15) * PAD + eo);
    short8 bfr[8];
#pragma unroll
    for (int nt = 0; nt < 8; ++nt)
      bfr[nt] = *(const short8*)(Wsb + (nt * 16 + l15) * PAD + eo);
#pragma unroll
    for (int nt = 0; nt < 8; ++nt)
      acc[nt] = __builtin_amdgcn_mfma_f32_16x16x32_bf16(af, bfr[nt], acc[nt], 0, 0, 0);
  }

  float* outp = (which ? Ct : Bt) + (size_t)n * Ll * Hh;
#pragma unroll
  for (int nt = 0; nt < 8; ++nt) {
    int g = nt * 16 + l15;
    float badd = which ? 0.f : b1[g];
#pragma unroll
    for (int r = 0; r < 4; ++r) {
      int k = mh * 64 + w * 16 + quad * 4 + r;
      outp[(size_t)k * Hh + g] = acc[nt][r] + badd;
    }
  }
}

// v5: R3 shell (one block per (n,t), t in [0,32), 4 compacted j's), but the
// GEMM processes j's in PAIRS sharing every W1a fragment read (the dominant
// marginal cost: 256 KB/j of ds_read_b128 -> ~72 KB/j). acc[2][8]=64 VGPRs;
// all epilogue operands loaded AFTER the GEMM (spill-safe at (512,4)=128).
__launch_bounds__(512, 4)
__global__ void k_main(const float* __restrict__ doc, const int* __restrict__ dmask,
                       const float* __restrict__ W1,
                       const float* __restrict__ w2, const float* __restrict__ b2,
                       const float* __restrict__ Bt, const float* __restrict__ Ct,
                       float* __restrict__ out) {
  __shared__ __align__(16) short As[Hh * PAD];    // bf16(W1a)
  __shared__ __align__(16) short docb[Hh * PAD];  // bf16(doc), raw
  __shared__ __align__(16) float sc[4][Ll];
  __shared__ __align__(16) float scw[4][Ll];
  __shared__ int jl[Ll], ml[Ll], cnts[4];

  int bid = blockIdx.x;
  int n = bid & 31, t = bid >> 5;   // same-n blocks cluster on an XCD
  int tid = threadIdx.x;
  int lane = tid & 63, wv = tid >> 6;
  const float* docn = doc + (size_t)n * Ll * Hh;
  const int* dmn = dmask + n * Ll;

  // ballot-compact the mask row (waves 0,1 only)
  int jme = -1, mflag = 0, pre = 0;
  if (wv < 2) {
    jme = (wv << 6) + lane;
    mflag = dmn[jme] != 0;
    unsigned long long bal = __ballot(mflag);
    pre = __popcll(bal & ((1ull << lane) - 1ull));
    if (lane == 0) { int tot = __popcll(bal); cnts[wv] = tot; cnts[2 + wv] = 64 - tot; }
  }
  __syncthreads();
  int cnt = cnts[0] + cnts[1];
  if (wv == 0) { if (mflag) jl[pre] = jme; else ml[lane - pre] = jme; }
  else if (wv == 1) { if (mflag) jl[cnts[0] + pre] = jme; else ml[cnts[2] + (lane - pre)] = jme; }
  __syncthreads();

  // zero-write this block's share of masked rows (4t+rr spans [0,128) uniquely)
  {
    int rr = tid >> 7, h = tid & 127;
    int mi = 4 * t + rr;
    if (mi < Ll - cnt) out[((size_t)n * Ll + ml[mi]) * Hh + h] = 0.f;
  }
  if (4 * t >= cnt) return;   // block-uniform

  // stage W1a + raw doc
  int e8 = (tid & 15) * 8;
#pragma unroll
  for (int p = 0; p < 4; ++p) {
    int row = p * 32 + (tid >> 4);
    const float4* wp = (const float4*)(W1 + (size_t)row * W1S + e8);
    *(short8*)(As + row * PAD + e8) = pack8(wp[0], wp[1]);
    const float4* dp = (const float4*)(docn + (size_t)row * Hh + e8);
    *(short8*)(docb + row * PAD + e8) = pack8(dp[0], dp[1]);
  }
  __syncthreads();

  int l15 = lane & 15, quad = lane >> 4;
  const float c2 = 2.885390081777927f;  // 2*log2(e)
  const float* ctn = Ct + (size_t)n * Ll * Hh;

  for (int pp = 0; pp < 2; ++pp) {
    int idx0 = 4 * t + 2 * pp;
    if (idx0 >= cnt) break;             // block-uniform
    int idx1 = idx0 + 1;
    int j0 = jl[idx0];
    int j1 = jl[idx1 < cnt ? idx1 : idx0];  // dup-safe tail
    const float* jr0 = docn + (size_t)j0 * Hh;
    const float* jr1 = docn + (size_t)j1 * Hh;

    floatx4 acc[2][8];
#pragma unroll
    for (int sj = 0; sj < 2; ++sj)
#pragma unroll
      for (int nt = 0; nt < 8; ++nt) acc[sj][nt] = (floatx4){0.f, 0.f, 0.f, 0.f};

#pragma unroll
    for (int c = 0; c < 4; ++c) {
      int eo = c * 32 + quad * 8;
      short8 dr = *(const short8*)(docb + (wv * 16 + l15) * PAD + eo);
      float d[8];
#pragma unroll
      for (int i = 0; i < 8; ++i) d[i] = bf2f(dr[i]);
      const float4* p0 = (const float4*)(jr0 + eo);  // quad-broadcast, L1-hot
      const float4* p1 = (const float4*)(jr1 + eo);
      float4 a0 = p0[0], b0 = p0[1];
      float4 a1 = p1[0], b1v = p1[1];
      float4 ta, tb;
      ta.x = d[0] * a0.x; ta.y = d[1] * a0.y; ta.z = d[2] * a0.z; ta.w = d[3] * a0.w;
      tb.x = d[4] * b0.x; tb.y = d[5] * b0.y; tb.z = d[6] * b0.z; tb.w = d[7] * b0.w;
      short8 af0 = pack8(ta, tb);
      ta.x = d[0] * a1.x; ta.y = d[1] * a1.y; ta.z = d[2] * a1.z; ta.w = d[3] * a1.w;
      tb.x = d[4] * b1v.x; tb.y = d[5] * b1v.y; tb.z = d[6] * b1v.z; tb.w = d[7] * b1v.w;
      short8 af1 = pack8(ta, tb);
#pragma unroll
      for (int nt = 0; nt < 8; ++nt) {
        short8 bfr = *(const short8*)(As + (nt * 16 + l15) * PAD + eo);
        acc[0][nt] = __builtin_amdgcn_mfma_f32_16x16x32_bf16(af0, bfr, acc[0][nt], 0, 0, 0);
        acc[1][nt] = __builtin_amdgcn_mfma_f32_16x16x32_bf16(af1, bfr, acc[1][nt], 0, 0, 0);
      }
    }

    // epilogue for each pair member -> sc[jj][k]
#pragma unroll
    for (int sj = 0; sj < 2; ++sj) {
      int idx = idx0 + sj;
      if (idx >= cnt) break;            // block-uniform
      int j = sj ? j1 : j0;
      int jj = 2 * pp + sj;
      float bbc[8], w2r[8];
      const float* btrow = Bt + ((size_t)n * Ll + j) * Hh;
#pragma unroll
      for (int nt = 0; nt < 8; ++nt) {
        int g = nt * 16 + l15;
        bbc[nt] = btrow[g] * c2;
        w2r[nt] = w2[g];
      }
#pragma unroll
      for (int r = 0; r < 4; ++r) {
        int k = wv * 16 + quad * 4 + r;
        const float* ctp = ctn + (size_t)k * Hh + l15;
        float p = 0.f;
#pragma unroll
        for (int nt = 0; nt < 8; ++nt) {
          float s = acc[sj][nt][r] + ctp[nt * 16];
          float a2 = fmaf(s, c2, bbc[nt]);
          float e = exp2f(a2);
          float th = fmaf(-2.f, __builtin_amdgcn_rcpf(e + 1.f), 1.f);
          p = fmaf(th, w2r[nt], p);
        }
        p += __shfl_xor(p, 1);
        p += __shfl_xor(p, 2);
        p += __shfl_xor(p, 4);
        p += __shfl_xor(p, 8);
        if (l15 == 0) sc[jj][k] = p;
      }
    }
  }
  __syncthreads();

  // masked softmax: wave jj handles j = jl[4t+jj]
  if (wv < 4) {
    int idx = 4 * t + wv;
    if (idx < cnt) {
      float b2v = b2[0];
      const float inv = 0.088388347648318447f;  // 1/sqrt(128)
      int m0 = dmn[lane], m1 = dmn[lane + 64];
      float s0 = (sc[wv][lane] + b2v) * inv;
      float s1 = (sc[wv][lane + 64] + b2v) * inv;
      s0 = m0 ? s0 : -1e9f;
      s1 = m1 ? s1 : -1e9f;
      float mx = fmaxf(s0, s1);
#pragma unroll
      for (int off = 32; off; off >>= 1) mx = fmaxf(mx, __shfl_xor(mx, off));
      float ex0 = __expf(s0 - mx), ex1 = __expf(s1 - mx);
      float sm = ex0 + ex1;
#pragma unroll
      for (int off = 32; off; off >>= 1) sm += __shfl_xor(sm, off);
      float rden = 1.f / sm;
      scw[wv][lane] = m0 ? ex0 * rden : 0.f;
      scw[wv][lane + 64] = m1 ? ex1 * rden : 0.f;
    } else {
      scw[wv][lane] = 0.f;
      scw[wv][lane + 64] = 0.f;
    }
  }
  __syncthreads();

  // fused AV: each doc load feeds 4 j-accumulators; k split in 4 quarters
  float* ored = (float*)As;  // [quarter][jj][h], As dead after GEMM
  {
    int qk = tid >> 7, h = tid & 127;   // qk in 0..3, 32 k's each
    const float* dbase = docn + (size_t)qk * 32 * Hh + h;
    float o0 = 0.f, o1 = 0.f, o2 = 0.f, o3 = 0.f;
#pragma unroll
    for (int k4 = 0; k4 < 8; ++k4) {
      float4 s0 = *(const float4*)&scw[0][qk * 32 + k4 * 4];
      float4 s1 = *(const float4*)&scw[1][qk * 32 + k4 * 4];
      float4 s2 = *(const float4*)&scw[2][qk * 32 + k4 * 4];
      float4 s3 = *(const float4*)&scw[3][qk * 32 + k4 * 4];
      float d0 = dbase[(size_t)(k4 * 4 + 0) * Hh];
      float d1 = dbase[(size_t)(k4 * 4 + 1) * Hh];
      float d2 = dbase[(size_t)(k4 * 4 + 2) * Hh];
      float d3 = dbase[(size_t)(k4 * 4 + 3) * Hh];
      o0 = fmaf(s0.x, d0, o0); o0 = fmaf(s0.y, d1, o0); o0 = fmaf(s0.z, d2, o0); o0 = fmaf(s0.w, d3, o0);
      o1 = fmaf(s1.x, d0, o1); o1 = fmaf(s1.y, d1, o1); o1 = fmaf(s1.z, d2, o1); o1 = fmaf(s1.w, d3, o1);
      o2 = fmaf(s2.x, d0, o2); o2 = fmaf(s2.y, d1, o2); o2 = fmaf(s2.z, d2, o2); o2 = fmaf(s2.w, d3, o2);
      o3 = fmaf(s3.x, d0, o3); o3 = fmaf(s3.y, d1, o3); o3 = fmaf(s3.z, d2, o3); o3 = fmaf(s3.w, d3, o3);
    }
    ored[(qk * 4 + 0) * Hh + h] = o0;
    ored[(qk * 4 + 1) * Hh + h] = o1;
    ored[(qk * 4 + 2) * Hh + h] = o2;
    ored[(qk * 4 + 3) * Hh + h] = o3;
  }
  __syncthreads();
  {
    int jj2 = tid >> 7, h = tid & 127;
    int idx = 4 * t + jj2;
    if (idx < cnt) {
      float v = ored[(0 * 4 + jj2) * Hh + h] + ored[(1 * 4 + jj2) * Hh + h] +
                ored[(2 * 4 + jj2) * Hh + h] + ored[(3 * 4 + jj2) * Hh + h];
      out[((size_t)n * Ll + jl[idx]) * Hh + h] = v;
    }
  }
}

extern "C" void kernel_launch(void* const* d_in, const int* in_sizes, int n_in,
                              void* d_out, int out_size, void* d_ws, size_t ws_size,
                              hipStream_t stream) {
  const float* wei   = (const float*)d_in[0];
  const int*   wmask = (const int*)d_in[1];
  const float* doc   = (const float*)d_in[2];
  const int*   dmask = (const int*)d_in[3];
  const float* q     = (const float*)d_in[4];
  const float* W1    = (const float*)d_in[5];
  const float* b1    = (const float*)d_in[6];
  const float* w2    = (const float*)d_in[7];
  const float* b2    = (const float*)d_in[8];
  float* out = (float*)d_out;

  float* ws = (float*)d_ws;
  float* Bt = ws;                           // N*L*H (b1 folded in)
  float* Ct = Bt + (size_t)Nn * Ll * Hh;    // N*L*H   (total 4.19 MB, unchanged)

  k_prep<<<Nn * 4, 256, 0, stream>>>(wei, wmask, doc, q, W1, b1, Bt, Ct);
  k_main<<<Nn * 32, 512, 0, stream>>>(doc, dmask, W1, w2, b2, Bt, Ct, out);
}

// Round 6
// 124.598 us; speedup vs baseline: 1.9809x; 1.0465x over previous
//
#include <hip/hip_runtime.h>
#include <hip/hip_bf16.h>
#include <math.h>

#define Hh 128   // hidden
#define Nn 32    // docs
#define Ll 128   // doc_len
#define W1S 384  // 3H
#define PAD 136  // bf16 elems per LDS row in k_prep (272B stride)
#define EP 64    // e-elems per K-pass in k_main
#define SP 72    // f16 elems per LDS row in k_main (144B stride, odd 16B-slot count)

typedef __attribute__((ext_vector_type(8))) short short8;
typedef __attribute__((ext_vector_type(4))) float floatx4;
typedef __attribute__((ext_vector_type(8))) _Float16 f16x8;

__device__ __forceinline__ unsigned short f2bf(float x) {
  __hip_bfloat16 h = __float2bfloat16(x);
  return __builtin_bit_cast(unsigned short, h);
}
__device__ __forceinline__ short8 pack8(float4 a, float4 b) {
  short8 r;
  r[0] = (short)f2bf(a.x); r[1] = (short)f2bf(a.y);
  r[2] = (short)f2bf(a.z); r[3] = (short)f2bf(a.w);
  r[4] = (short)f2bf(b.x); r[5] = (short)f2bf(b.y);
  r[6] = (short)f2bf(b.z); r[7] = (short)f2bf(b.w);
  return r;
}
__device__ __forceinline__ f16x8 cvt8h(float4 a, float4 b) {
  f16x8 r;
  r[0] = (_Float16)a.x; r[1] = (_Float16)a.y;
  r[2] = (_Float16)a.z; r[3] = (_Float16)a.w;
  r[4] = (_Float16)b.x; r[5] = (_Float16)b.y;
  r[6] = (_Float16)b.z; r[7] = (_Float16)b.w;
  return r;
}

// Grid 128: block b -> n = b>>2, which = (b>>1)&1 (0:Bt 1:Ct), mh = b&1 (M-half).
// scale folded at staging; b1 folded into Bt so k_main skips it. (unchanged)
__launch_bounds__(256, 2)
__global__ void k_prep(const float* __restrict__ wei, const int* __restrict__ wmask,
                       const float* __restrict__ doc, const float* __restrict__ q,
                       const float* __restrict__ W1, const float* __restrict__ b1,
                       float* __restrict__ Bt, float* __restrict__ Ct) {
  __shared__ __align__(16) short Wsb[Hh * PAD];   // bf16(W1b or W1c)
  __shared__ __align__(16) short docb[64 * PAD];  // bf16(doc * scale), this block's 64 rows
  __shared__ __align__(16) float red[2][Hh];
  __shared__ __align__(16) float scale[Hh];

  int b = blockIdx.x;
  int n = b >> 2, which = (b >> 1) & 1, mh = b & 1;
  int tid = threadIdx.x;
  const float* docn = doc + (size_t)n * Ll * Hh;
  int e8 = (tid & 15) * 8;

  float4 dreg[4][2];
#pragma unroll
  for (int p = 0; p < 4; ++p) {
    int row = mh * 64 + p * 16 + (tid >> 4);
    const float4* dp = (const float4*)(docn + (size_t)row * Hh + e8);
    dreg[p][0] = dp[0]; dreg[p][1] = dp[1];
  }
#pragma unroll
  for (int p = 0; p < 8; ++p) {
    int row = p * 16 + (tid >> 4);
    const float4* wp = (const float4*)(W1 + (size_t)row * W1S + (which + 1) * Hh + e8);
    *(short8*)(Wsb + row * PAD + e8) = pack8(wp[0], wp[1]);
  }
  if (which == 1) {
    if (tid < Hh) scale[tid] = q[(n >> 3) * Hh + tid];
  } else {
    int e = tid & 127, halfl = tid >> 7;
    const float* wp = wei + (size_t)n * Ll * Hh + (size_t)halfl * 64 * Hh + e;
    const int* mp = wmask + n * Ll + halfl * 64;
    float a = 0.f;
#pragma unroll 16
    for (int l = 0; l < 64; ++l) a = fmaf((float)mp[l], wp[(size_t)l * Hh], a);
    red[halfl][e] = a;
  }
  __syncthreads();
  if (which == 0 && tid < Hh) scale[tid] = red[0][tid] + red[1][tid];
  __syncthreads();
  {
    float s[8];
#pragma unroll
    for (int i = 0; i < 8; ++i) s[i] = scale[e8 + i];
#pragma unroll
    for (int p = 0; p < 4; ++p) {
      int r = p * 16 + (tid >> 4);
      float4 a = dreg[p][0], bq = dreg[p][1];
      a.x *= s[0]; a.y *= s[1]; a.z *= s[2]; a.w *= s[3];
      bq.x *= s[4]; bq.y *= s[5]; bq.z *= s[6]; bq.w *= s[7];
      *(short8*)(docb + r * PAD + e8) = pack8(a, bq);
    }
  }
  __syncthreads();

  int lane = tid & 63, w = tid >> 6;
  int l15 = lane & 15, quad = lane >> 4;
  floatx4 acc[8];
#pragma unroll
  for (int nt = 0; nt < 8; ++nt) acc[nt] = (floatx4){0.f, 0.f, 0.f, 0.f};
#pragma unroll
  for (int c = 0; c < 4; ++c) {
    int eo = c * 32 + quad * 8;
    short8 af = *(const short8*)(docb + (w * 16 + l15) * PAD + eo);
    short8 bfr[8];
#pragma unroll
    for (int nt = 0; nt < 8; ++nt)
      bfr[nt] = *(const short8*)(Wsb + (nt * 16 + l15) * PAD + eo);
#pragma unroll
    for (int nt = 0; nt < 8; ++nt)
      acc[nt] = __builtin_amdgcn_mfma_f32_16x16x32_bf16(af, bfr[nt], acc[nt], 0, 0, 0);
  }

  float* outp = (which ? Ct : Bt) + (size_t)n * Ll * Hh;
#pragma unroll
  for (int nt = 0; nt < 8; ++nt) {
    int g = nt * 16 + l15;
    float badd = which ? 0.f : b1[g];
#pragma unroll
    for (int r = 0; r < 4; ++r) {
      int k = mh * 64 + w * 16 + quad * 4 + r;
      outp[(size_t)k * Hh + g] = acc[nt][r] + badd;
    }
  }
}

// v6: one block per (n,j) (R1 shell), fp16 operands, K-SPLIT staging:
// only a 64-wide e-window of doc and W1a lives in LDS per pass (two passes,
// acc accumulates across). LDS ~37.9 KB -> 3 blocks/CU; launch_bounds (512,6)
// targets <=85 VGPR -> 24 waves/CU. af-build = 4 v_pk_mul_f16 per pass
// (was ~26-instr bf16 unpack/mul/cvt chain per c).
__launch_bounds__(512, 6)
__global__ void k_main(const float* __restrict__ doc, const int* __restrict__ dmask,
                       const float* __restrict__ W1,
                       const float* __restrict__ w2, const float* __restrict__ b2,
                       const float* __restrict__ Bt, const float* __restrict__ Ct,
                       float* __restrict__ out) {
  __shared__ __align__(16) _Float16 As[Hh * SP];  // fp16(W1a), e-window
  __shared__ __align__(16) _Float16 Bs[Hh * SP];  // fp16(doc), e-window
  __shared__ __align__(16) float sc[Ll];
  __shared__ __align__(16) float scw[Ll];

  int bid = blockIdx.x;
  int n = bid & 31, j = bid >> 5;   // XCD-locality swizzle
  int tid = threadIdx.x;
  const float* docn = doc + (size_t)n * Ll * Hh;
  size_t orow = ((size_t)n * Ll + j) * Hh;

  if (dmask[n * Ll + j] == 0) {     // fully-masked row -> exact zeros (~50% of blocks)
    if (tid < Hh) out[orow + tid] = 0.f;
    return;
  }

  int lane = tid & 63, wv = tid >> 6;   // 8 waves x 16 k-rows
  int l15 = lane & 15, quad = lane >> 4;
  int grow = tid >> 2, seg = (tid & 3) * 16;  // staging: row 0..127, 16-e segment

  floatx4 acc[8];
#pragma unroll
  for (int nt = 0; nt < 8; ++nt) acc[nt] = (floatx4){0.f, 0.f, 0.f, 0.f};

#pragma unroll
  for (int p = 0; p < 2; ++p) {
    if (p) __syncthreads();  // all waves done reading pass-0 window
    // stage this pass's 64-e window of doc and W1a as fp16
    {
      const float4* dsrc = (const float4*)(docn + (size_t)grow * Hh + p * EP + seg);
      const float4* wsrc = (const float4*)(W1 + (size_t)grow * W1S + p * EP + seg);
      float4 d0 = dsrc[0], d1 = dsrc[1], d2 = dsrc[2], d3 = dsrc[3];
      float4 w0 = wsrc[0], w1 = wsrc[1], w2v = wsrc[2], w3 = wsrc[3];
      *(f16x8*)(Bs + grow * SP + seg) = cvt8h(d0, d1);
      *(f16x8*)(Bs + grow * SP + seg + 8) = cvt8h(d2, d3);
      *(f16x8*)(As + grow * SP + seg) = cvt8h(w0, w1);
      *(f16x8*)(As + grow * SP + seg + 8) = cvt8h(w2v, w3);
    }
    __syncthreads();
    // GEMM over this 64-e window
#pragma unroll
    for (int c = 0; c < 2; ++c) {
      int eo = c * 32 + quad * 8;
      f16x8 dr = *(const f16x8*)(Bs + (wv * 16 + l15) * SP + eo);
      f16x8 jr = *(const f16x8*)(Bs + j * SP + eo);   // quad-broadcast
      f16x8 af = dr * jr;                              // 4x v_pk_mul_f16
#pragma unroll
      for (int nt = 0; nt < 8; ++nt) {
        f16x8 bfr = *(const f16x8*)(As + (nt * 16 + l15) * SP + eo);
        acc[nt] = __builtin_amdgcn_mfma_f32_16x16x32_f16(af, bfr, acc[nt], 0, 0, 0);
      }
    }
  }

  // epilogue: tanh(acc + Ct[k,g] + Bt[j,g]) . w2 -> sc[k]   (b1 folded into Bt)
  const float c2 = 2.885390081777927f;  // 2*log2(e)
  float bbc[8], w2r[8];
  const float* btrow = Bt + orow;
#pragma unroll
  for (int nt = 0; nt < 8; ++nt) {
    int g = nt * 16 + l15;
    bbc[nt] = btrow[g] * c2;
    w2r[nt] = w2[g];
  }
  const float* ctn = Ct + (size_t)n * Ll * Hh;
#pragma unroll
  for (int r = 0; r < 4; ++r) {
    int k = wv * 16 + quad * 4 + r;
    const float* ctp = ctn + (size_t)k * Hh + l15;
    float p = 0.f;
#pragma unroll
    for (int nt = 0; nt < 8; ++nt) {
      float s = acc[nt][r] + ctp[nt * 16];
      float a2 = fmaf(s, c2, bbc[nt]);
      float e = exp2f(a2);
      float th = fmaf(-2.f, __builtin_amdgcn_rcpf(e + 1.f), 1.f);
      p = fmaf(th, w2r[nt], p);
    }
    p += __shfl_xor(p, 1);
    p += __shfl_xor(p, 2);
    p += __shfl_xor(p, 4);
    p += __shfl_xor(p, 8);
    if (l15 == 0) sc[k] = p;
  }
  __syncthreads();

  // redundant per-wave masked softmax (no extra barriers)
  {
    float b2v = b2[0];
    const float inv = 0.088388347648318447f;  // 1/sqrt(128)
    const int* dmn = dmask + n * Ll;
    int m0 = dmn[lane], m1 = dmn[lane + 64];
    float s0 = (sc[lane] + b2v) * inv;
    float s1 = (sc[lane + 64] + b2v) * inv;
    s0 = m0 ? s0 : -1e9f;
    s1 = m1 ? s1 : -1e9f;
    float mx = fmaxf(s0, s1);
#pragma unroll
    for (int off = 32; off; off >>= 1) mx = fmaxf(mx, __shfl_xor(mx, off));
    float ex0 = __expf(s0 - mx), ex1 = __expf(s1 - mx);
    float sm = ex0 + ex1;
#pragma unroll
    for (int off = 32; off; off >>= 1) sm += __shfl_xor(sm, off);
    float rden = 1.f / sm;
    scw[lane] = m0 ? ex0 * rden : 0.f;       // all 8 waves write identical values
    scw[lane + 64] = m1 ? ex1 * rden : 0.f;
  }
  __syncthreads();

  // out[j,h] = sum_k w[k] * doc[n,k,h] ; 4-way k-split across the 512 threads
  float* ored = (float*)As;  // As dead after GEMM (all waves past last barrier)
  int qk = tid >> 7, h = tid & 127;
  const float* dbase = docn + (size_t)qk * 32 * Hh + h;
  float o = 0.f;
#pragma unroll 8
  for (int kk = 0; kk < 32; ++kk)
    o = fmaf(scw[qk * 32 + kk], dbase[(size_t)kk * Hh], o);
  ored[qk * Hh + h] = o;
  __syncthreads();
  if (tid < Ll)
    out[orow + tid] = ored[tid] + ored[Hh + tid] + ored[2 * Hh + tid] + ored[3 * Hh + tid];
}

extern "C" void kernel_launch(void* const* d_in, const int* in_sizes, int n_in,
                              void* d_out, int out_size, void* d_ws, size_t ws_size,
                              hipStream_t stream) {
  const float* wei   = (const float*)d_in[0];
  const int*   wmask = (const int*)d_in[1];
  const float* doc   = (const float*)d_in[2];
  const int*   dmask = (const int*)d_in[3];
  const float* q     = (const float*)d_in[4];
  const float* W1    = (const float*)d_in[5];
  const float* b1    = (const float*)d_in[6];
  const float* w2    = (const float*)d_in[7];
  const float* b2    = (const float*)d_in[8];
  float* out = (float*)d_out;

  float* ws = (float*)d_ws;
  float* Bt = ws;                           // N*L*H (b1 folded in)
  float* Ct = Bt + (size_t)Nn * Ll * Hh;    // N*L*H   (total 4.19 MB, unchanged)

  k_prep<<<Nn * 4, 256, 0, stream>>>(wei, wmask, doc, q, W1, b1, Bt, Ct);
  k_main<<<Nn * Ll, 512, 0, stream>>>(doc, dmask, W1, w2, b2, Bt, Ct, out);
}